// Round 2
// baseline (7766.467 us; speedup 1.0000x reference)
//
#include <hip/hip_runtime.h>
#include <stdint.h>

#define NBOX 1024
#define BLK  256

typedef unsigned long long u64;
typedef unsigned short u16;
typedef unsigned char  u8;

// ---------- bit-exact IoU (matches numpy f32 op-for-op; _rn blocks FMA contraction) ----------
__device__ __forceinline__ float iou_pair(const float4 lb, float larea,
                                          const float4 pb, float parea) {
    float ix1 = fmaxf(lb.x, pb.x);
    float iy1 = fmaxf(lb.y, pb.y);
    float ix2 = fminf(lb.z, pb.z);
    float iy2 = fminf(lb.w, pb.w);
    float w = fmaxf(__fsub_rn(ix2, ix1), 0.0f);
    float h = fmaxf(__fsub_rn(iy2, iy1), 0.0f);
    float inter = __fmul_rn(w, h);
    float denom = __fsub_rn(__fadd_rn(larea, parea), inter);
    return inter / denom;
}

__device__ __forceinline__ u64 umax64(u64 a, u64 b) { return a > b ? a : b; }

__device__ __forceinline__ u64 shflx64(u64 v, int mask) {
    unsigned lo = __shfl_xor((unsigned)(v & 0xffffffffull), mask, 64);
    unsigned hi = __shfl_xor((unsigned)(v >> 32), mask, 64);
    return (((u64)hi) << 32) | lo;
}

// =====================================================================================
// Kernel A (parallel, whole GPU): JM[b][c] = IoU(label b, pred c)  +  per-row (max,col)
// =====================================================================================
__global__ void __launch_bounds__(BLK) jm_init(const float* __restrict__ labels,
                                               const float* __restrict__ preds,
                                               float* __restrict__ JM,
                                               u64* __restrict__ key_ws,
                                               u16* __restrict__ col_ws) {
    __shared__ float wv[4];
    __shared__ int   wc[4];
    const int b = blockIdx.x;
    const int t = threadIdx.x, lane = t & 63, wid = t >> 6;
    float4 lb = ((const float4*)labels)[b];
    float larea = __fmul_rn(__fsub_rn(lb.z, lb.x), __fsub_rn(lb.w, lb.y));
    float bv = -1.0f; int bc = 0;
    #pragma unroll
    for (int k = 0; k < 4; ++k) {
        int c = t + (k << 8);
        float4 pb = ((const float4*)preds)[c];
        float parea = __fmul_rn(__fsub_rn(pb.z, pb.x), __fsub_rn(pb.w, pb.y));
        float v = iou_pair(lb, larea, pb, parea);
        JM[b * NBOX + c] = v;
        if (v > bv || (v == bv && c > bc)) { bv = v; bc = c; }
    }
    for (int off = 32; off > 0; off >>= 1) {
        float ov = __shfl_xor(bv, off, 64);
        int   oc = __shfl_xor(bc, off, 64);
        if (ov > bv || (ov == bv && oc > bc)) { bv = ov; bc = oc; }
    }
    if (lane == 0) { wv[wid] = bv; wc[wid] = bc; }
    __syncthreads();
    if (t == 0) {
        float fv = wv[0]; int fc = wc[0];
        for (int w = 1; w < 4; ++w)
            if (wv[w] > fv || (wv[w] == fv && wc[w] > fc)) { fv = wv[w]; fc = wc[w]; }
        key_ws[b] = ((u64)__float_as_uint(fv) << 11) | ((unsigned)b << 1) | 1ull;
        col_ws[b] = (u16)fc;
    }
}

// =====================================================================================
// Kernel B: SINGLE-WAVE sequential greedy (no barriers) + final L1 loss
//   key[row]  : (f32bits<<11)|(row<<1)|1  in LDS; 0 == row masked
//   colv[row] : argmax col | 0x8000 live-bit; 0 == dead
//   per-lane running max (lmax,largmax) kept incrementally; dirty -> recompute
// =====================================================================================
__global__ void __launch_bounds__(64, 1)
greedy1w(const float* __restrict__ preds,
         const float* __restrict__ labels,
         const float* __restrict__ JM,
         const u64* __restrict__ key_ws,
         const u16* __restrict__ col_ws,
         float* __restrict__ out) {
    __shared__ u64 key[NBOX];
    __shared__ u16 colv[NBOX];
    __shared__ u16 perm[NBOX];
    __shared__ u8  seen[NBOX];
    __shared__ u16 list[NBOX];
    __shared__ int listn;

    const int lane = threadIdx.x;

    #pragma unroll
    for (int j = 0; j < 16; ++j) {
        int i = lane + (j << 6);
        key[i]  = key_ws[i];
        colv[i] = col_ws[i] | 0x8000;
        perm[i] = (u16)i;
        seen[i] = 0;
    }
    if (lane == 0) listn = 0;

    u64 lmax = 0; int largmax = -1; bool dirty = true;

    for (int step = 0; step < NBOX; ++step) {
        if (dirty) {
            lmax = 0; largmax = -1;
            #pragma unroll
            for (int j = 0; j < 16; ++j) {
                int i = lane + (j << 6);
                u64 k = key[i];
                if (k > lmax) { lmax = k; largmax = i; }
            }
            dirty = false;
        }
        // ---- global pick: butterfly max over 64 lanes ----
        u64 kb = lmax;
        for (int off = 32; off > 0; off >>= 1) kb = umax64(kb, shflx64(kb, off));
        if ((kb >> 11) == 0ull) break;          // max IoU == 0.0 -> remaining steps no-ops
        const int r = (int)((kb >> 1) & 1023);
        const int c = (int)(colv[r] & 1023);

        int pr = perm[r], pc = perm[c];          // all lanes read BEFORE write
        if (lane == 0) {
            perm[r] = (u16)pc; perm[c] = (u16)pr;
            seen[c] = 1;
            key[c] = 0;
            colv[c] = 0;                          // kill live-bit
            listn = 0;
        }
        if (lane == (c & 63) && largmax == c) dirty = true;

        // ---- rows whose live argmax column is c (includes r itself) ----
        const u16 match = (u16)(c | 0x8000);
        #pragma unroll
        for (int j = 0; j < 16; ++j) {
            int row = lane + (j << 6);
            if (colv[row] == match) { int ix = atomicAdd(&listn, 1); list[ix] = (u16)row; }
        }
        const int n = listn;

        // ---- rescan listed rows from JM, two at a time (interleaved butterflies) ----
        for (int base = 0; base < n; base += 2) {
            const int ra = list[base];
            const bool hb = (base + 1 < n);
            const int rb = hb ? list[base + 1] : ra;
            const int pa = perm[ra], pb = perm[rb];
            const float* Ja = JM + pa * NBOX;
            const float* Jb = JM + pb * NBOX;
            float bva = -1.0f, bvb = -1.0f; int bca = 0, bcb = 0;
            #pragma unroll
            for (int j = 0; j < 16; ++j) {
                int cc = lane + (j << 6);
                float va = Ja[cc];
                float vb = Jb[cc];
                if (!seen[cc]) {
                    if (va > bva || (va == bva && cc > bca)) { bva = va; bca = cc; }
                    if (vb > bvb || (vb == bvb && cc > bcb)) { bvb = vb; bcb = cc; }
                }
            }
            for (int off = 32; off > 0; off >>= 1) {
                float ova = __shfl_xor(bva, off, 64); int oca = __shfl_xor(bca, off, 64);
                float ovb = __shfl_xor(bvb, off, 64); int ocb = __shfl_xor(bcb, off, 64);
                if (ova > bva || (ova == bva && oca > bca)) { bva = ova; bca = oca; }
                if (ovb > bvb || (ovb == bvb && ocb > bcb)) { bvb = ovb; bcb = ocb; }
            }
            if (bva < 0.0f) bva = 0.0f;           // "no valid col" -> val 0 (exit handles)
            if (bvb < 0.0f) bvb = 0.0f;
            const u64 ka  = ((u64)__float_as_uint(bva) << 11) | ((unsigned)ra << 1) | 1ull;
            const u64 kb2 = ((u64)__float_as_uint(bvb) << 11) | ((unsigned)rb << 1) | 1ull;
            if (lane == 0) {
                key[ra] = ka; colv[ra] = (u16)(bca | 0x8000);
                if (hb) { key[rb] = kb2; colv[rb] = (u16)(bcb | 0x8000); }
            }
            if (lane == (ra & 63)) {
                if (ka > lmax) { lmax = ka; largmax = ra; }
                else if (largmax == ra) dirty = true;
            }
            if (hb && lane == (rb & 63)) {
                if (kb2 > lmax) { lmax = kb2; largmax = rb; }
                else if (largmax == rb) dirty = true;
            }
        }
    }

    // ---- loss = mean |labels[perm] - predictions| ----
    float sum = 0.0f;
    #pragma unroll
    for (int j = 0; j < 16; ++j) {
        int i = lane + (j << 6);
        float4 pb = ((const float4*)preds)[i];
        float4 lb = ((const float4*)labels)[perm[i]];
        sum += fabsf(lb.x - pb.x) + fabsf(lb.y - pb.y) +
               fabsf(lb.z - pb.z) + fabsf(lb.w - pb.w);
    }
    for (int off = 32; off > 0; off >>= 1) sum += __shfl_xor(sum, off, 64);
    if (lane == 0) out[0] = sum * (1.0f / 4096.0f);
}

// =====================================================================================
// Fallback (proven R1 path): 4-wave block kernel, optional ws-assisted init
// =====================================================================================
__global__ void init_rowmax(const float* __restrict__ labels,
                            const float* __restrict__ preds,
                            u64* __restrict__ key_ws,
                            u16* __restrict__ col_ws) {
    const int b = blockIdx.x;
    const int lane = threadIdx.x;
    float4 lb = ((const float4*)labels)[b];
    float larea = __fmul_rn(__fsub_rn(lb.z, lb.x), __fsub_rn(lb.w, lb.y));
    float bv = -1.0f; int bc = 0;
    #pragma unroll 4
    for (int j = 0; j < 16; ++j) {
        int c = lane + (j << 6);
        float4 pb = ((const float4*)preds)[c];
        float parea = __fmul_rn(__fsub_rn(pb.z, pb.x), __fsub_rn(pb.w, pb.y));
        float v = iou_pair(lb, larea, pb, parea);
        if (v > bv || (v == bv && c > bc)) { bv = v; bc = c; }
    }
    for (int off = 32; off > 0; off >>= 1) {
        float ov = __shfl_xor(bv, off, 64);
        int   oc = __shfl_xor(bc, off, 64);
        if (ov > bv || (ov == bv && oc > bc)) { bv = ov; bc = oc; }
    }
    if (lane == 0) {
        key_ws[b] = ((u64)__float_as_uint(bv) << 11) | ((unsigned)b << 1) | 1ull;
        col_ws[b] = (u16)bc;
    }
}

__global__ void __launch_bounds__(BLK, 1)
greedy_kernel(const float* __restrict__ preds,
              const float* __restrict__ labels,
              const u64* __restrict__ key_ws,
              const u16* __restrict__ col_ws,
              float* __restrict__ out) {
    __shared__ u64 key[NBOX];
    __shared__ u16 colv[NBOX];
    __shared__ int perm[NBOX];
    __shared__ u8  seen[NBOX];
    __shared__ u16 list[NBOX];
    __shared__ float4 pred4[NBOX];
    __shared__ float4 lab4[NBOX];
    __shared__ float  parea_s[NBOX];
    __shared__ u64 part[4];
    __shared__ float fpart[4];
    __shared__ int listn;

    const int t = threadIdx.x, lane = t & 63, wid = t >> 6;

    for (int k = 0; k < 4; ++k) {
        int i = t + k * BLK;
        perm[i] = i; seen[i] = 0;
        float4 p = ((const float4*)preds)[i];
        pred4[i] = p;
        lab4[i]  = ((const float4*)labels)[i];
        parea_s[i] = __fmul_rn(__fsub_rn(p.z, p.x), __fsub_rn(p.w, p.y));
        if (key_ws) { key[i] = key_ws[i]; colv[i] = col_ws[i]; }
    }
    if (t == 0) listn = 0;
    __syncthreads();

    auto scan_row = [&](int row, int p) {
        float4 lb = lab4[p];
        float larea = __fmul_rn(__fsub_rn(lb.z, lb.x), __fsub_rn(lb.w, lb.y));
        float bv = -1.0f; int bc = 0;
        #pragma unroll 4
        for (int j = 0; j < 16; ++j) {
            int cc = lane + (j << 6);
            if (!seen[cc]) {
                float v = iou_pair(lb, larea, pred4[cc], parea_s[cc]);
                if (v > bv || (v == bv && cc > bc)) { bv = v; bc = cc; }
            }
        }
        for (int off = 32; off > 0; off >>= 1) {
            float ov = __shfl_xor(bv, off, 64);
            int   oc = __shfl_xor(bc, off, 64);
            if (ov > bv || (ov == bv && oc > bc)) { bv = ov; bc = oc; }
        }
        if (lane == 0) {
            key[row]  = ((u64)__float_as_uint(bv) << 11) | ((unsigned)row << 1) | 1ull;
            colv[row] = (u16)bc;
        }
    };

    if (!key_ws) {
        for (int row = wid; row < NBOX; row += 4) scan_row(row, row);
        __syncthreads();
    }

    for (int step = 0; step < NBOX; ++step) {
        u64 km = umax64(umax64(key[t], key[t + 256]), umax64(key[t + 512], key[t + 768]));
        for (int off = 32; off > 0; off >>= 1) km = umax64(km, shflx64(km, off));
        if (lane == 0) part[wid] = km;
        __syncthreads();
        u64 kb = umax64(umax64(part[0], part[1]), umax64(part[2], part[3]));
        if ((kb >> 11) == 0ull) break;
        const int r = (int)((kb >> 1) & 1023);
        const int c = (int)colv[r];
        if (t == 0) {
            listn = 0;
            int pr = perm[r], pc = perm[c];
            perm[r] = pc; perm[c] = pr;
            seen[c] = 1; key[c] = 0;
            if (r != c) { list[0] = (u16)r; listn = 1; }
        }
        __syncthreads();
        for (int k = 0; k < 4; ++k) {
            int row = t + k * BLK;
            if (row != r && (int)colv[row] == c && !seen[row]) {
                int idx = atomicAdd(&listn, 1);
                list[idx] = (u16)row;
            }
        }
        __syncthreads();
        const int n = listn;
        for (int base = 0; base < n; base += 4) {
            int li = base + wid;
            if (li < n) { int row = list[li]; scan_row(row, perm[row]); }
        }
        __syncthreads();
    }

    __syncthreads();
    float sum = 0.0f;
    for (int k = 0; k < 4; ++k) {
        int i = t + k * BLK;
        float4 lb = lab4[perm[i]];
        float4 pr = pred4[i];
        sum += fabsf(lb.x - pr.x) + fabsf(lb.y - pr.y) +
               fabsf(lb.z - pr.z) + fabsf(lb.w - pr.w);
    }
    for (int off = 32; off > 0; off >>= 1) sum += __shfl_xor(sum, off, 64);
    if (lane == 0) fpart[wid] = sum;
    __syncthreads();
    if (t == 0) out[0] = (fpart[0] + fpart[1] + fpart[2] + fpart[3]) * (1.0f / 4096.0f);
}

extern "C" void kernel_launch(void* const* d_in, const int* in_sizes, int n_in,
                              void* d_out, int out_size, void* d_ws, size_t ws_size,
                              hipStream_t stream) {
    const float* preds  = (const float*)d_in[0];
    const float* labels = (const float*)d_in[1];
    float* out = (float*)d_out;

    const size_t jm_bytes  = (size_t)NBOX * NBOX * sizeof(float);        // 4 MB
    const size_t key_bytes = NBOX * sizeof(u64);
    const size_t col_bytes = NBOX * sizeof(u16);

    if (d_ws && ws_size >= jm_bytes + key_bytes + col_bytes) {
        float* JM     = (float*)d_ws;
        u64*   key_ws = (u64*)((char*)d_ws + jm_bytes);
        u16*   col_ws = (u16*)((char*)d_ws + jm_bytes + key_bytes);
        jm_init<<<NBOX, BLK, 0, stream>>>(labels, preds, JM, key_ws, col_ws);
        greedy1w<<<1, 64, 0, stream>>>(preds, labels, JM, key_ws, col_ws, out);
    } else if (d_ws && ws_size >= key_bytes + col_bytes) {
        u64* key_ws = (u64*)d_ws;
        u16* col_ws = (u16*)((char*)d_ws + key_bytes);
        init_rowmax<<<NBOX, 64, 0, stream>>>(labels, preds, key_ws, col_ws);
        greedy_kernel<<<1, BLK, 0, stream>>>(preds, labels, key_ws, col_ws, out);
    } else {
        greedy_kernel<<<1, BLK, 0, stream>>>(preds, labels, nullptr, nullptr, out);
    }
}

// Round 3
// 3435.928 us; speedup vs baseline: 2.2604x; 2.2604x over previous
//
#include <hip/hip_runtime.h>
#include <stdint.h>

#define NBOX 1024
#define BLK  256

typedef unsigned long long u64;
typedef unsigned short u16;

// ---------- bit-exact IoU (matches numpy f32 op-for-op; _rn blocks FMA contraction) ----------
__device__ __forceinline__ float iou_pair(const float4 lb, float larea,
                                          const float4 pb, float parea) {
    float ix1 = fmaxf(lb.x, pb.x);
    float iy1 = fmaxf(lb.y, pb.y);
    float ix2 = fminf(lb.z, pb.z);
    float iy2 = fminf(lb.w, pb.w);
    float w = fmaxf(__fsub_rn(ix2, ix1), 0.0f);
    float h = fmaxf(__fsub_rn(iy2, iy1), 0.0f);
    float inter = __fmul_rn(w, h);
    float denom = __fsub_rn(__fadd_rn(larea, parea), inter);
    return inter / denom;
}

__device__ __forceinline__ u64 umax64(u64 a, u64 b) { return a > b ? a : b; }

// ---------- 64-lane u64 max-reduce via DPP (rocPRIM pattern); result valid in lane 63 ----------
__device__ __forceinline__ u64 dpp_max64(u64 v) {
    unsigned lo, hi; u64 o;
#define DPP_STEP(CTRL) \
    lo = (unsigned)__builtin_amdgcn_update_dpp(0, (int)(unsigned)(v & 0xffffffffull), CTRL, 0xf, 0xf, true); \
    hi = (unsigned)__builtin_amdgcn_update_dpp(0, (int)(unsigned)(v >> 32),           CTRL, 0xf, 0xf, true); \
    o = (((u64)hi) << 32) | lo; \
    if (o > v) v = o;
    DPP_STEP(0x111);  /* row_shr:1  */
    DPP_STEP(0x112);  /* row_shr:2  */
    DPP_STEP(0x114);  /* row_shr:4  */
    DPP_STEP(0x118);  /* row_shr:8  */
    DPP_STEP(0x142);  /* row_bcast15 */
    DPP_STEP(0x143);  /* row_bcast31 */
#undef DPP_STEP
    return v;
}

// =====================================================================================
// Kernel A (parallel, 1024 blocks): initial packed key per row
//   key = (ioubits<<21) | (row<<11) | (col<<1) | 1   (0 == dead row)
// =====================================================================================
__global__ void __launch_bounds__(64) init_rowmax(const float* __restrict__ labels,
                                                  const float* __restrict__ preds,
                                                  u64* __restrict__ key_ws) {
    const int b = blockIdx.x;
    const int lane = threadIdx.x;
    float4 lb = ((const float4*)labels)[b];
    float larea = __fmul_rn(__fsub_rn(lb.z, lb.x), __fsub_rn(lb.w, lb.y));
    float bv = -1.0f; int bc = 0;
    #pragma unroll
    for (int j = 0; j < 16; ++j) {
        int c = lane + (j << 6);
        float4 pb = ((const float4*)preds)[c];
        float parea = __fmul_rn(__fsub_rn(pb.z, pb.x), __fsub_rn(pb.w, pb.y));
        float v = iou_pair(lb, larea, pb, parea);
        if (v > bv || (v == bv && c > bc)) { bv = v; bc = c; }
    }
    u64 pv = ((u64)__float_as_uint(bv) << 10) | (unsigned)bc;
    pv = dpp_max64(pv);
    if (lane == 63)
        key_ws[b] = ((pv >> 10) << 21) | ((u64)b << 11) | ((pv & 1023ull) << 1) | 1ull;
}

// =====================================================================================
// Kernel B: 4-wave sequential greedy, 1 barrier/step, register-resident keys + final L1
// =====================================================================================
__global__ void __launch_bounds__(BLK, 1)
greedy4w(const float* __restrict__ preds,
         const float* __restrict__ labels,
         const u64* __restrict__ key_ws,   // may be null
         float* __restrict__ out) {
    __shared__ float4 pred4s[NBOX];
    __shared__ float4 lab4s[NBOX];
    __shared__ float  parea_s[NBOX];
    __shared__ float  larea_s[NBOX];
    __shared__ u16    perm[NBOX];
    __shared__ u64    part[2][4];
    __shared__ float  fpart[4];

    const int t    = (int)threadIdx.x;
    const int lane = t & 63;
    const int wid  = t >> 6;

    // ---- stage boxes + areas + identity perm ----
    #pragma unroll
    for (int k = 0; k < 4; ++k) {
        int i = t + (k << 8);
        float4 p = ((const float4*)preds)[i];
        float4 L = ((const float4*)labels)[i];
        pred4s[i] = p;
        lab4s[i]  = L;
        parea_s[i] = __fmul_rn(__fsub_rn(p.z, p.x), __fsub_rn(p.w, p.y));
        larea_s[i] = __fmul_rn(__fsub_rn(L.z, L.x), __fsub_rn(L.w, L.y));
        perm[i] = (u16)i;
    }

    // register-resident keys for this thread's 4 rows: t, t+256, t+512, t+768
    u64 k0 = 0, k1 = 0, k2 = 0, k3 = 0;
    unsigned myseen = 0;   // bit j == column (lane + j*64) consumed

    if (key_ws) {
        k0 = key_ws[t];
        k1 = key_ws[t + 256];
        k2 = key_ws[t + 512];
        k3 = key_ws[t + 768];
    }
    __syncthreads();

    // wave-cooperative rescan of one row over currently-unseen columns
    auto rescan = [&](int row) -> u64 {
        int pm = (int)perm[row];
        float4 lb = lab4s[pm];
        float la = larea_s[pm];
        float bv = -1.0f; int bc = 0;
        #pragma unroll
        for (int j = 0; j < 16; ++j) {
            int cc = lane + (j << 6);
            if (!((myseen >> j) & 1u)) {
                float v = iou_pair(lb, la, pred4s[cc], parea_s[cc]);
                if (v > bv || (v == bv && cc > bc)) { bv = v; bc = cc; }
            }
        }
        if (bv < 0.0f) { bv = 0.0f; bc = 0; }
        u64 pv = ((u64)__float_as_uint(bv) << 10) | (unsigned)bc;
        pv = dpp_max64(pv);
        unsigned plo = (unsigned)__builtin_amdgcn_readlane((int)(unsigned)(pv & 0xffffffffull), 63);
        unsigned phi = (unsigned)__builtin_amdgcn_readlane((int)(unsigned)(pv >> 32), 63);
        u64 pvm = (((u64)phi) << 32) | plo;
        return ((pvm >> 10) << 21) | ((u64)row << 11) | ((pvm & 1023ull) << 1) | 1ull;
    };

    // assign nk to the owner thread's register for `row` (row is wave-uniform)
    auto assign_key = [&](int row, u64 nk) {
        if (t == (row & 255)) {
            int j = row >> 8;
            if (j == 0) k0 = nk;
            else if (j == 1) k1 = nk;
            else if (j == 2) k2 = nk;
            else k3 = nk;
        }
    };

    if (!key_ws) {  // fallback init: each wave scans its own 256 rows
        for (int idx = 0; idx < 256; ++idx) {
            int row = (wid << 6) + (idx & 63) + ((idx >> 6) << 8);
            u64 nk = rescan(row);
            assign_key(row, nk);
        }
    }

    // ---- sequential greedy: 1 barrier per step ----
    for (int step = 0; step < NBOX; ++step) {
        u64 m = umax64(umax64(k0, k1), umax64(k2, k3));
        m = dpp_max64(m);
        const int sb = step & 1;
        if (lane == 63) part[sb][wid] = m;
        __syncthreads();                                    // the ONLY barrier
        u64 kb = umax64(umax64(part[sb][0], part[sb][1]),
                        umax64(part[sb][2], part[sb][3]));
        if ((kb >> 21) == 0ull) break;   // max IoU == 0.0 -> remaining picks are (i,i) no-ops
        const int r = (int)((kb >> 11) & 1023);
        const int c = (int)((kb >> 1) & 1023);

        assign_key(c, 0ull);                                // kill row c (register)
        if (lane == (c & 63)) myseen |= 1u << (c >> 6);     // mark column c seen (register)

        if (wid == ((r >> 6) & 3) && lane == 0) {           // perm swap: r's owner wave only
            u16 pr = perm[r], pc = perm[c];
            perm[r] = pc; perm[c] = pr;
        }

        // rows (among my 4) whose live argmax column is c  — includes r itself
        const u64 tag = ((u64)(unsigned)c << 1) | 1ull;
        unsigned hm = 0;
        if ((k0 & 0x7FFull) == tag) hm |= 1u;
        if ((k1 & 0x7FFull) == tag) hm |= 2u;
        if ((k2 & 0x7FFull) == tag) hm |= 4u;
        if ((k3 & 0x7FFull) == tag) hm |= 8u;

        unsigned long long bal = __ballot(hm != 0u);        // wave-scoped, uniform
        while (bal) {
            int l = (int)__ffsll((unsigned long long)bal) - 1;
            bal &= bal - 1;
            unsigned lhm = (unsigned)__builtin_amdgcn_readlane((int)hm, l);
            while (lhm) {
                int kk = (int)__ffs(lhm) - 1;
                lhm &= lhm - 1;
                int row = (wid << 6) + l + (kk << 8);
                u64 nk = rescan(row);
                assign_key(row, nk);
            }
        }
        // no second barrier: key state is register/wave-local; part[] is double-buffered
    }

    // ---- loss = mean |labels[perm] - predictions|  (same summation tree as R1) ----
    float sum = 0.0f;
    #pragma unroll
    for (int k = 0; k < 4; ++k) {
        int i = t + (k << 8);
        float4 lb = lab4s[perm[i]];
        float4 pr = pred4s[i];
        sum += fabsf(lb.x - pr.x) + fabsf(lb.y - pr.y) +
               fabsf(lb.z - pr.z) + fabsf(lb.w - pr.w);
    }
    for (int off = 32; off > 0; off >>= 1) sum += __shfl_xor(sum, off, 64);
    if (lane == 0) fpart[wid] = sum;
    __syncthreads();
    if (t == 0) out[0] = (fpart[0] + fpart[1] + fpart[2] + fpart[3]) * (1.0f / 4096.0f);
}

extern "C" void kernel_launch(void* const* d_in, const int* in_sizes, int n_in,
                              void* d_out, int out_size, void* d_ws, size_t ws_size,
                              hipStream_t stream) {
    const float* preds  = (const float*)d_in[0];   // predictions [1024,4]
    const float* labels = (const float*)d_in[1];   // labels      [1024,4]
    float* out = (float*)d_out;

    const size_t key_bytes = NBOX * sizeof(u64);   // 8 KB
    if (d_ws && ws_size >= key_bytes) {
        u64* key_ws = (u64*)d_ws;
        init_rowmax<<<NBOX, 64, 0, stream>>>(labels, preds, key_ws);
        greedy4w<<<1, BLK, 0, stream>>>(preds, labels, key_ws, out);
    } else {
        greedy4w<<<1, BLK, 0, stream>>>(preds, labels, nullptr, out);
    }
}

// Round 4
// 2593.283 us; speedup vs baseline: 2.9948x; 1.3249x over previous
//
#include <hip/hip_runtime.h>
#include <stdint.h>

#define NBOX 1024

typedef unsigned long long u64;
typedef unsigned short u16;

// ---------- bit-exact IoU (matches numpy f32 op-for-op; _rn blocks FMA contraction) ----------
__device__ __forceinline__ float iou_pair(const float4 lb, float larea,
                                          const float4 pb, float parea) {
    float ix1 = fmaxf(lb.x, pb.x);
    float iy1 = fmaxf(lb.y, pb.y);
    float ix2 = fminf(lb.z, pb.z);
    float iy2 = fminf(lb.w, pb.w);
    float w = fmaxf(__fsub_rn(ix2, ix1), 0.0f);
    float h = fmaxf(__fsub_rn(iy2, iy1), 0.0f);
    float inter = __fmul_rn(w, h);
    float denom = __fsub_rn(__fadd_rn(larea, parea), inter);
    return inter / denom;
}

__device__ __forceinline__ u64 umax64(u64 a, u64 b) { return a > b ? a : b; }

// ---------- 64-lane u64 max-reduce via DPP (rocPRIM pattern); result valid in lane 63 ----------
__device__ __forceinline__ u64 dpp_max64(u64 v) {
    unsigned lo, hi; u64 o;
#define DPP_STEP(CTRL) \
    lo = (unsigned)__builtin_amdgcn_update_dpp(0, (int)(unsigned)(v & 0xffffffffull), CTRL, 0xf, 0xf, true); \
    hi = (unsigned)__builtin_amdgcn_update_dpp(0, (int)(unsigned)(v >> 32),           CTRL, 0xf, 0xf, true); \
    o = (((u64)hi) << 32) | lo; \
    if (o > v) v = o;
    DPP_STEP(0x111);  /* row_shr:1  */
    DPP_STEP(0x112);  /* row_shr:2  */
    DPP_STEP(0x114);  /* row_shr:4  */
    DPP_STEP(0x118);  /* row_shr:8  */
    DPP_STEP(0x142);  /* row_bcast15 */
    DPP_STEP(0x143);  /* row_bcast31 */
#undef DPP_STEP
    return v;
}

__device__ __forceinline__ u64 readlane64(u64 v, int l) {
    unsigned lo = (unsigned)__builtin_amdgcn_readlane((int)(unsigned)(v & 0xffffffffull), l);
    unsigned hi = (unsigned)__builtin_amdgcn_readlane((int)(unsigned)(v >> 32), l);
    return (((u64)hi) << 32) | lo;
}

// =====================================================================================
// Kernel A (parallel, 1024 blocks): initial packed key per row
//   key = (ioubits<<21) | (row<<11) | (col<<1) | 1 ;  0 == dead row (max IoU == 0)
// =====================================================================================
__global__ void __launch_bounds__(64) init_rowmax(const float* __restrict__ labels,
                                                  const float* __restrict__ preds,
                                                  u64* __restrict__ key_ws) {
    const int b = blockIdx.x;
    const int lane = threadIdx.x;
    float4 lb = ((const float4*)labels)[b];
    float larea = __fmul_rn(__fsub_rn(lb.z, lb.x), __fsub_rn(lb.w, lb.y));
    float bv = -1.0f; int bc = 0;
    #pragma unroll
    for (int j = 0; j < 16; ++j) {
        int c = lane + (j << 6);
        float4 pb = ((const float4*)preds)[c];
        float parea = __fmul_rn(__fsub_rn(pb.z, pb.x), __fsub_rn(pb.w, pb.y));
        float v = iou_pair(lb, larea, pb, parea);
        if (v > bv || (v == bv && c > bc)) { bv = v; bc = c; }
    }
    u64 pv = ((u64)__float_as_uint(bv) << 10) | (unsigned)bc;
    pv = dpp_max64(pv);
    if (lane == 63) {
        u64 val = pv >> 10;
        key_ws[b] = val ? ((val << 21) | ((u64)b << 11) | ((pv & 1023ull) << 1) | 1ull)
                        : 0ull;
    }
}

// =====================================================================================
// Kernel B: SINGLE-WAVE greedy. All 1024 keys in 16 named u64 regs/lane; no barriers.
//   zero-kill + key-transfer-on-swap; rescans only when a row's argmax col is consumed.
// =====================================================================================

// uniform-j read of this lane's key register
#define SEL_KEY(jv, dst) do { switch (jv) { \
    case 0:  dst = kk0;  break; case 1:  dst = kk1;  break; \
    case 2:  dst = kk2;  break; case 3:  dst = kk3;  break; \
    case 4:  dst = kk4;  break; case 5:  dst = kk5;  break; \
    case 6:  dst = kk6;  break; case 7:  dst = kk7;  break; \
    case 8:  dst = kk8;  break; case 9:  dst = kk9;  break; \
    case 10: dst = kk10; break; case 11: dst = kk11; break; \
    case 12: dst = kk12; break; case 13: dst = kk13; break; \
    case 14: dst = kk14; break; default: dst = kk15; break; } } while (0)

// uniform-row assignment: owner lane (row&63) sets register (row>>6) to nk
#define ASSIGN_KEY(rowv, nk) do { int _j = (rowv) >> 6; bool _own = (lane == ((rowv) & 63)); \
    switch (_j) { \
    case 0:  if (_own) kk0  = (nk); break; case 1:  if (_own) kk1  = (nk); break; \
    case 2:  if (_own) kk2  = (nk); break; case 3:  if (_own) kk3  = (nk); break; \
    case 4:  if (_own) kk4  = (nk); break; case 5:  if (_own) kk5  = (nk); break; \
    case 6:  if (_own) kk6  = (nk); break; case 7:  if (_own) kk7  = (nk); break; \
    case 8:  if (_own) kk8  = (nk); break; case 9:  if (_own) kk9  = (nk); break; \
    case 10: if (_own) kk10 = (nk); break; case 11: if (_own) kk11 = (nk); break; \
    case 12: if (_own) kk12 = (nk); break; case 13: if (_own) kk13 = (nk); break; \
    case 14: if (_own) kk14 = (nk); break; default: if (_own) kk15 = (nk); break; } } while (0)

__global__ void __launch_bounds__(64, 1)
greedy1w(const float* __restrict__ preds,
         const float* __restrict__ labels,
         const u64* __restrict__ key_ws,   // may be null
         float* __restrict__ out) {
    __shared__ float4 pred4s[NBOX];
    __shared__ float4 lab4s[NBOX];
    __shared__ float  parea_s[NBOX];
    __shared__ float  larea_s[NBOX];
    __shared__ u16    perm[NBOX];

    const int lane = (int)threadIdx.x;

    #pragma unroll
    for (int j = 0; j < 16; ++j) {
        int i = lane + (j << 6);
        float4 p = ((const float4*)preds)[i];
        float4 L = ((const float4*)labels)[i];
        pred4s[i] = p;
        lab4s[i]  = L;
        parea_s[i] = __fmul_rn(__fsub_rn(p.z, p.x), __fsub_rn(p.w, p.y));
        larea_s[i] = __fmul_rn(__fsub_rn(L.z, L.x), __fsub_rn(L.w, L.y));
        perm[i] = (u16)i;
    }

    u64 kk0, kk1, kk2, kk3, kk4, kk5, kk6, kk7;
    u64 kk8, kk9, kk10, kk11, kk12, kk13, kk14, kk15;
    unsigned myseen = 0;   // bit j: column (lane + 64j) consumed

    // wave-cooperative rescan of one (uniform) row over currently-unseen columns.
    // returns packed key for that row (0 if max IoU == 0 -> permanently dead).
    auto rescan = [&](int row) -> u64 {
        int pm = (int)perm[row];
        float4 lb = lab4s[pm];
        float la = larea_s[pm];
        u64 best = 0;
        #pragma unroll
        for (int j2 = 0; j2 < 16; ++j2) {
            int cc = lane + (j2 << 6);
            float v = iou_pair(lb, la, pred4s[cc], parea_s[cc]);
            u64 pv = ((u64)__float_as_uint(v) << 10) | (unsigned)cc;
            if ((myseen >> j2) & 1u) pv = 0;   // masked col
            best = umax64(best, pv);
        }
        best = dpp_max64(best);
        u64 bm = readlane64(best, 63);
        u64 val = bm >> 10;
        return val ? ((val << 21) | ((u64)row << 11) | ((bm & 1023ull) << 1) | 1ull)
                   : 0ull;
    };

    if (key_ws) {
        kk0  = key_ws[lane];        kk1  = key_ws[lane + 64];
        kk2  = key_ws[lane + 128];  kk3  = key_ws[lane + 192];
        kk4  = key_ws[lane + 256];  kk5  = key_ws[lane + 320];
        kk6  = key_ws[lane + 384];  kk7  = key_ws[lane + 448];
        kk8  = key_ws[lane + 512];  kk9  = key_ws[lane + 576];
        kk10 = key_ws[lane + 640];  kk11 = key_ws[lane + 704];
        kk12 = key_ws[lane + 768];  kk13 = key_ws[lane + 832];
        kk14 = key_ws[lane + 896];  kk15 = key_ws[lane + 960];
    } else {
        kk0 = kk1 = kk2 = kk3 = kk4 = kk5 = kk6 = kk7 = 0;
        kk8 = kk9 = kk10 = kk11 = kk12 = kk13 = kk14 = kk15 = 0;
        for (int row = 0; row < NBOX; ++row) {
            u64 nk = rescan(row);
            ASSIGN_KEY(row, nk);
        }
    }

    for (int step = 0; step < NBOX; ++step) {
        // ---- global pick: 16-reg tree + DPP butterfly ----
        u64 m = umax64(umax64(umax64(kk0, kk1),  umax64(kk2, kk3)),
                       umax64(umax64(kk4, kk5),  umax64(kk6, kk7)));
        m = umax64(m, umax64(umax64(umax64(kk8, kk9),   umax64(kk10, kk11)),
                             umax64(umax64(kk12, kk13), umax64(kk14, kk15))));
        m = dpp_max64(m);
        u64 kb = readlane64(m, 63);
        if (!kb) break;                        // global max IoU == 0 -> perm final
        const int r = (int)((kb >> 11) & 1023);
        const int c = (int)((kb >> 1) & 1023);

        // ---- read old key[c] (describes the content row r is about to receive) ----
        const int jc = c >> 6, lc = c & 63;
        u64 vc; SEL_KEY(jc, vc);
        u64 kc = readlane64(vc, lc);

        // ---- perm swap (all lanes read, lane 0 writes) ----
        int ppr = (int)perm[r], ppc = (int)perm[c];
        if (lane == 0) { perm[r] = (u16)ppc; perm[c] = (u16)ppr; }

        // ---- key transfer r <- retag(key[c]); kill row c; mark col c seen ----
        u64 kcp = kc ? ((kc & ~0x1FF800ull) | ((u64)(unsigned)r << 11)) : 0ull;
        ASSIGN_KEY(r, kcp);
        ASSIGN_KEY(c, 0ull);                   // overwrites transfer when r == c
        if (lane == lc) myseen |= 1u << jc;

        // ---- rows whose live argmax column is c (includes transferred r if stale) ----
        const u64 tag = ((u64)(unsigned)c << 1) | 1ull;
        unsigned hm = 0;
        if ((kk0  & 0x7FFull) == tag) hm |= 1u << 0;
        if ((kk1  & 0x7FFull) == tag) hm |= 1u << 1;
        if ((kk2  & 0x7FFull) == tag) hm |= 1u << 2;
        if ((kk3  & 0x7FFull) == tag) hm |= 1u << 3;
        if ((kk4  & 0x7FFull) == tag) hm |= 1u << 4;
        if ((kk5  & 0x7FFull) == tag) hm |= 1u << 5;
        if ((kk6  & 0x7FFull) == tag) hm |= 1u << 6;
        if ((kk7  & 0x7FFull) == tag) hm |= 1u << 7;
        if ((kk8  & 0x7FFull) == tag) hm |= 1u << 8;
        if ((kk9  & 0x7FFull) == tag) hm |= 1u << 9;
        if ((kk10 & 0x7FFull) == tag) hm |= 1u << 10;
        if ((kk11 & 0x7FFull) == tag) hm |= 1u << 11;
        if ((kk12 & 0x7FFull) == tag) hm |= 1u << 12;
        if ((kk13 & 0x7FFull) == tag) hm |= 1u << 13;
        if ((kk14 & 0x7FFull) == tag) hm |= 1u << 14;
        if ((kk15 & 0x7FFull) == tag) hm |= 1u << 15;

        unsigned long long bal = __ballot(hm != 0u);
        while (bal) {
            int l = (int)__ffsll(bal) - 1;
            bal &= bal - 1;
            unsigned lhm = (unsigned)__builtin_amdgcn_readlane((int)hm, l);
            while (lhm) {
                int jj = (int)__ffs(lhm) - 1;
                lhm &= lhm - 1;
                int row = l + (jj << 6);
                u64 nk = rescan(row);
                ASSIGN_KEY(row, nk);
            }
        }
    }

    // ---- loss = mean |labels[perm] - predictions| ----
    float sum = 0.0f;
    #pragma unroll
    for (int j = 0; j < 16; ++j) {
        int i = lane + (j << 6);
        float4 pb = pred4s[i];
        float4 lb = lab4s[perm[i]];
        sum += fabsf(lb.x - pb.x) + fabsf(lb.y - pb.y) +
               fabsf(lb.z - pb.z) + fabsf(lb.w - pb.w);
    }
    for (int off = 32; off > 0; off >>= 1) sum += __shfl_xor(sum, off, 64);
    if (lane == 0) out[0] = sum * (1.0f / 4096.0f);
}

extern "C" void kernel_launch(void* const* d_in, const int* in_sizes, int n_in,
                              void* d_out, int out_size, void* d_ws, size_t ws_size,
                              hipStream_t stream) {
    const float* preds  = (const float*)d_in[0];   // predictions [1024,4]
    const float* labels = (const float*)d_in[1];   // labels      [1024,4]
    float* out = (float*)d_out;

    const size_t key_bytes = NBOX * sizeof(u64);   // 8 KB
    if (d_ws && ws_size >= key_bytes) {
        u64* key_ws = (u64*)d_ws;
        init_rowmax<<<NBOX, 64, 0, stream>>>(labels, preds, key_ws);
        greedy1w<<<1, 64, 0, stream>>>(preds, labels, key_ws, out);
    } else {
        greedy1w<<<1, 64, 0, stream>>>(preds, labels, nullptr, out);
    }
}

// Round 5
// 2269.842 us; speedup vs baseline: 3.4216x; 1.1425x over previous
//
#include <hip/hip_runtime.h>
#include <stdint.h>

#define NBOX 1024

typedef unsigned long long u64;
typedef unsigned short u16;

// ---------- bit-exact IoU (matches numpy f32 op-for-op; _rn blocks FMA contraction) ----------
__device__ __forceinline__ float iou_pair(const float4 lb, float larea,
                                          const float4 pb, float parea) {
    float ix1 = fmaxf(lb.x, pb.x);
    float iy1 = fmaxf(lb.y, pb.y);
    float ix2 = fminf(lb.z, pb.z);
    float iy2 = fminf(lb.w, pb.w);
    float w = fmaxf(__fsub_rn(ix2, ix1), 0.0f);
    float h = fmaxf(__fsub_rn(iy2, iy1), 0.0f);
    float inter = __fmul_rn(w, h);
    float denom = __fsub_rn(__fadd_rn(larea, parea), inter);
    return inter / denom;
}

__device__ __forceinline__ u64 umax64(u64 a, u64 b) { return a > b ? a : b; }

// ---------- 64-lane u64 max-reduce via DPP; result valid in lane 63 ----------
__device__ __forceinline__ u64 dpp_max64(u64 v) {
    unsigned lo, hi; u64 o;
#define DPP_STEP(CTRL) \
    lo = (unsigned)__builtin_amdgcn_update_dpp(0, (int)(unsigned)(v & 0xffffffffull), CTRL, 0xf, 0xf, true); \
    hi = (unsigned)__builtin_amdgcn_update_dpp(0, (int)(unsigned)(v >> 32),           CTRL, 0xf, 0xf, true); \
    o = (((u64)hi) << 32) | lo; \
    if (o > v) v = o;
    DPP_STEP(0x111);  /* row_shr:1  */
    DPP_STEP(0x112);  /* row_shr:2  */
    DPP_STEP(0x114);  /* row_shr:4  */
    DPP_STEP(0x118);  /* row_shr:8  */
    DPP_STEP(0x142);  /* row_bcast15 */
    DPP_STEP(0x143);  /* row_bcast31 */
#undef DPP_STEP
    return v;
}

__device__ __forceinline__ u64 readlane64(u64 v, int l) {
    unsigned lo = (unsigned)__builtin_amdgcn_readlane((int)(unsigned)(v & 0xffffffffull), l);
    unsigned hi = (unsigned)__builtin_amdgcn_readlane((int)(unsigned)(v >> 32), l);
    return (((u64)hi) << 32) | lo;
}

// =====================================================================================
// Kernel A (parallel, 1024 blocks): initial packed key per row
//   key = (ioubits<<21) | (row<<11) | (col<<1) | 1 ;  0 == dead row (max IoU == 0)
// =====================================================================================
__global__ void __launch_bounds__(64) init_rowmax(const float* __restrict__ labels,
                                                  const float* __restrict__ preds,
                                                  u64* __restrict__ key_ws) {
    const int b = blockIdx.x;
    const int lane = threadIdx.x;
    float4 lb = ((const float4*)labels)[b];
    float larea = __fmul_rn(__fsub_rn(lb.z, lb.x), __fsub_rn(lb.w, lb.y));
    float bv = -1.0f; int bc = 0;
    #pragma unroll
    for (int j = 0; j < 16; ++j) {
        int c = lane + (j << 6);
        float4 pb = ((const float4*)preds)[c];
        float parea = __fmul_rn(__fsub_rn(pb.z, pb.x), __fsub_rn(pb.w, pb.y));
        float v = iou_pair(lb, larea, pb, parea);
        if (v > bv || (v == bv && c > bc)) { bv = v; bc = c; }
    }
    u64 pv = ((u64)__float_as_uint(bv) << 10) | (unsigned)bc;
    pv = dpp_max64(pv);
    if (lane == 63) {
        u64 val = pv >> 10;
        key_ws[b] = val ? ((val << 21) | ((u64)b << 11) | ((pv & 1023ull) << 1) | 1ull)
                        : 0ull;
    }
}

// =====================================================================================
// Kernel B: SINGLE-WAVE lazy greedy. Keys are upper bounds; validate-at-pick.
// =====================================================================================

// branchless uniform-j read of this lane's key register
#define SEL_KEY(jv, dst) do { \
    dst = ((jv) == 0)  ? kk0  : dst; dst = ((jv) == 1)  ? kk1  : dst; \
    dst = ((jv) == 2)  ? kk2  : dst; dst = ((jv) == 3)  ? kk3  : dst; \
    dst = ((jv) == 4)  ? kk4  : dst; dst = ((jv) == 5)  ? kk5  : dst; \
    dst = ((jv) == 6)  ? kk6  : dst; dst = ((jv) == 7)  ? kk7  : dst; \
    dst = ((jv) == 8)  ? kk8  : dst; dst = ((jv) == 9)  ? kk9  : dst; \
    dst = ((jv) == 10) ? kk10 : dst; dst = ((jv) == 11) ? kk11 : dst; \
    dst = ((jv) == 12) ? kk12 : dst; dst = ((jv) == 13) ? kk13 : dst; \
    dst = ((jv) == 14) ? kk14 : dst; dst = ((jv) == 15) ? kk15 : dst; } while (0)

// branchless uniform-row assignment: owner lane (row&63) sets register (row>>6)
#define ASSIGN_KEY(rowv, nk) do { \
    const int _j = (rowv) >> 6; const bool _own = (lane == ((rowv) & 63)); \
    kk0  = (_own && _j == 0)  ? (nk) : kk0;  kk1  = (_own && _j == 1)  ? (nk) : kk1;  \
    kk2  = (_own && _j == 2)  ? (nk) : kk2;  kk3  = (_own && _j == 3)  ? (nk) : kk3;  \
    kk4  = (_own && _j == 4)  ? (nk) : kk4;  kk5  = (_own && _j == 5)  ? (nk) : kk5;  \
    kk6  = (_own && _j == 6)  ? (nk) : kk6;  kk7  = (_own && _j == 7)  ? (nk) : kk7;  \
    kk8  = (_own && _j == 8)  ? (nk) : kk8;  kk9  = (_own && _j == 9)  ? (nk) : kk9;  \
    kk10 = (_own && _j == 10) ? (nk) : kk10; kk11 = (_own && _j == 11) ? (nk) : kk11; \
    kk12 = (_own && _j == 12) ? (nk) : kk12; kk13 = (_own && _j == 13) ? (nk) : kk13; \
    kk14 = (_own && _j == 14) ? (nk) : kk14; kk15 = (_own && _j == 15) ? (nk) : kk15; } while (0)

__global__ void __launch_bounds__(64, 1)
greedy1w(const float* __restrict__ preds,
         const float* __restrict__ labels,
         const u64* __restrict__ key_ws,   // may be null
         float* __restrict__ out) {
    __shared__ float4 pred4s[NBOX];
    __shared__ float4 lab4s[NBOX];
    __shared__ float  parea_s[NBOX];
    __shared__ float  larea_s[NBOX];
    __shared__ u16    perm[NBOX];

    const int lane = (int)threadIdx.x;

    #pragma unroll
    for (int j = 0; j < 16; ++j) {
        int i = lane + (j << 6);
        float4 p = ((const float4*)preds)[i];
        float4 L = ((const float4*)labels)[i];
        pred4s[i] = p;
        lab4s[i]  = L;
        parea_s[i] = __fmul_rn(__fsub_rn(p.z, p.x), __fsub_rn(p.w, p.y));
        larea_s[i] = __fmul_rn(__fsub_rn(L.z, L.x), __fsub_rn(L.w, L.y));
        perm[i] = (u16)i;
    }

    u64 kk0, kk1, kk2, kk3, kk4, kk5, kk6, kk7;
    u64 kk8, kk9, kk10, kk11, kk12, kk13, kk14, kk15;
    unsigned myseen = 0;   // bit j: column (lane + 64j) consumed

    // wave-cooperative exact rescan of one (uniform) row over unseen columns
    auto rescan = [&](int row) -> u64 {
        int pm = (int)perm[row];
        float4 lb = lab4s[pm];
        float la = larea_s[pm];
        u64 best = 0;
        #pragma unroll
        for (int j2 = 0; j2 < 16; ++j2) {
            int cc = lane + (j2 << 6);
            float v = iou_pair(lb, la, pred4s[cc], parea_s[cc]);
            u64 pv = ((u64)__float_as_uint(v) << 10) | (unsigned)cc;
            if ((myseen >> j2) & 1u) pv = 0;
            best = umax64(best, pv);
        }
        best = dpp_max64(best);
        u64 bm = readlane64(best, 63);
        u64 val = bm >> 10;
        return val ? ((val << 21) | ((u64)row << 11) | ((bm & 1023ull) << 1) | 1ull)
                   : 0ull;
    };

    if (key_ws) {
        kk0  = key_ws[lane];        kk1  = key_ws[lane + 64];
        kk2  = key_ws[lane + 128];  kk3  = key_ws[lane + 192];
        kk4  = key_ws[lane + 256];  kk5  = key_ws[lane + 320];
        kk6  = key_ws[lane + 384];  kk7  = key_ws[lane + 448];
        kk8  = key_ws[lane + 512];  kk9  = key_ws[lane + 576];
        kk10 = key_ws[lane + 640];  kk11 = key_ws[lane + 704];
        kk12 = key_ws[lane + 768];  kk13 = key_ws[lane + 832];
        kk14 = key_ws[lane + 896];  kk15 = key_ws[lane + 960];
    } else {
        kk0 = kk1 = kk2 = kk3 = kk4 = kk5 = kk6 = kk7 = 0;
        kk8 = kk9 = kk10 = kk11 = kk12 = kk13 = kk14 = kk15 = 0;
        for (int row = 0; row < NBOX; ++row) {
            u64 nk = rescan(row);
            ASSIGN_KEY(row, nk);
        }
    }

    // ---- lazy greedy: pick max bound, validate, commit or rescan-and-repick ----
    for (int iter = 0; iter < 8192; ++iter) {
        u64 m = umax64(umax64(umax64(kk0, kk1),  umax64(kk2, kk3)),
                       umax64(umax64(kk4, kk5),  umax64(kk6, kk7)));
        m = umax64(m, umax64(umax64(umax64(kk8, kk9),   umax64(kk10, kk11)),
                             umax64(umax64(kk12, kk13), umax64(kk14, kk15))));
        m = dpp_max64(m);
        u64 kb = readlane64(m, 63);
        if (!kb) break;                       // all live true-max == 0 -> perm final
        const int r  = (int)((kb >> 11) & 1023);
        const int c  = (int)((kb >> 1) & 1023);
        const int jc = c >> 6, lc = c & 63;

        // validate: winner's stored col still unseen?
        unsigned sl = (unsigned)__builtin_amdgcn_readlane((int)myseen, lc);
        if ((sl >> jc) & 1u) {
            u64 nk = rescan(r);               // exact refresh; key strictly decreases
            ASSIGN_KEY(r, nk);
            continue;                         // re-pick
        }

        // ---- commit (key is exact): transfer key c -> r, kill c, mark col c ----
        u64 vc = 0; SEL_KEY(jc, vc);
        u64 kc = readlane64(vc, lc);          // old key of row c (bound for r's new content)

        int ppr = (int)perm[r], ppc = (int)perm[c];
        if (lane == 0) { perm[r] = (u16)ppc; perm[c] = (u16)ppr; }

        u64 kcp = kc ? ((kc & ~0x1FF800ull) | ((u64)(unsigned)r << 11)) : 0ull;
        ASSIGN_KEY(r, kcp);
        ASSIGN_KEY(c, 0ull);                  // overwrites transfer when r == c
        if (lane == lc) myseen |= 1u << jc;
    }

    // ---- loss = mean |labels[perm] - predictions| ----
    float sum = 0.0f;
    #pragma unroll
    for (int j = 0; j < 16; ++j) {
        int i = lane + (j << 6);
        float4 pb = pred4s[i];
        float4 lb = lab4s[perm[i]];
        sum += fabsf(lb.x - pb.x) + fabsf(lb.y - pb.y) +
               fabsf(lb.z - pb.z) + fabsf(lb.w - pb.w);
    }
    for (int off = 32; off > 0; off >>= 1) sum += __shfl_xor(sum, off, 64);
    if (lane == 0) out[0] = sum * (1.0f / 4096.0f);
}

extern "C" void kernel_launch(void* const* d_in, const int* in_sizes, int n_in,
                              void* d_out, int out_size, void* d_ws, size_t ws_size,
                              hipStream_t stream) {
    const float* preds  = (const float*)d_in[0];   // predictions [1024,4]
    const float* labels = (const float*)d_in[1];   // labels      [1024,4]
    float* out = (float*)d_out;

    const size_t key_bytes = NBOX * sizeof(u64);   // 8 KB
    if (d_ws && ws_size >= key_bytes) {
        u64* key_ws = (u64*)d_ws;
        init_rowmax<<<NBOX, 64, 0, stream>>>(labels, preds, key_ws);
        greedy1w<<<1, 64, 0, stream>>>(preds, labels, key_ws, out);
    } else {
        greedy1w<<<1, 64, 0, stream>>>(preds, labels, nullptr, out);
    }
}